// Round 2
// baseline (170.782 us; speedup 1.0000x reference)
//
#include <hip/hip_runtime.h>
#include <hip/hip_bf16.h>

// BiPairwiseNegativeCELoss on MI355X.
// Inputs: q, d, nd : [16384, 128] fp32. Output: scalar fp32 loss.
// loss = 0.5 * ( mean(softplus(q.nd_row - q.d_row))
//              + mean(softplus(max_c(q_b . d_c, diag -1e6) - q_b.d_b)) )

#define BATCH 16384
#define DDIM  128
#define ROWS_PER_BLOCK 64
#define NWAVES 8                // 512 threads: 2 waves/SIMD for MFMA/VALU overlap
#define COLS_PER_WAVE  (BATCH / NWAVES)               // 2048
#define CHUNK_COLS     16       // 16 cols x 128 k x bf16 = 4 KB per buffer
#define NCHUNKS        (COLS_PER_WAVE / CHUNK_COLS)   // 128

typedef __attribute__((ext_vector_type(8))) short bf16x8;   // 8 bf16 = 4 VGPRs
typedef __attribute__((ext_vector_type(4))) float f32x4;

__device__ __forceinline__ float softplus_f(float x) {
    return (x > 0.0f) ? x + log1pf(expf(-x)) : log1pf(expf(x));
}

__device__ __forceinline__ ushort f2bf_rne(float x) {
    unsigned u = __float_as_uint(x);
    unsigned r = (u + 0x7FFFu + ((u >> 16) & 1u)) >> 16;
    return (ushort)r;
}

// ---------------------------------------------------------------------------
// Kernel A: single pass over q/d/nd -- pairwise dots (fp32 exact), loss1
// partial sums, bf16 casts. 256 blocks x 256 threads; block owns 64 rows.
// Each i-iteration: 256 threads cover 8 rows (32 threads x 4 elems per row).
// ---------------------------------------------------------------------------
__global__ __launch_bounds__(256) void prep_kernel(
    const float* __restrict__ q, const float* __restrict__ d,
    const float* __restrict__ nd,
    ushort* __restrict__ qb, ushort* __restrict__ db,
    float* __restrict__ pos, float* __restrict__ acc)
{
    const int t   = threadIdx.x;
    const int blk = blockIdx.x;
    const int sub = t >> 5;       // row-group 0..7 within each i
    const int ln  = t & 31;       // 32 threads per row
    const size_t base = (size_t)blk * (ROWS_PER_BLOCK * DDIM);

    float loss1 = 0.0f;
#pragma unroll
    for (int i = 0; i < 8; ++i) {
        size_t idx = base + (size_t)i * 1024 + (size_t)t * 4;
        float4 a = *(const float4*)(q  + idx);
        float4 b = *(const float4*)(d  + idx);
        float4 c = *(const float4*)(nd + idx);

        ushort4 o;
        o.x = f2bf_rne(a.x); o.y = f2bf_rne(a.y);
        o.z = f2bf_rne(a.z); o.w = f2bf_rne(a.w);
        *(ushort4*)(qb + idx) = o;
        ushort4 p;
        p.x = f2bf_rne(b.x); p.y = f2bf_rne(b.y);
        p.z = f2bf_rne(b.z); p.w = f2bf_rne(b.w);
        *(ushort4*)(db + idx) = p;

        float ps = a.x * b.x + a.y * b.y + a.z * b.z + a.w * b.w;
        float ns = a.x * c.x + a.y * c.y + a.z * c.z + a.w * c.w;
        ps += __shfl_xor(ps, 1); ps += __shfl_xor(ps, 2);
        ps += __shfl_xor(ps, 4); ps += __shfl_xor(ps, 8);
        ps += __shfl_xor(ps, 16);
        ns += __shfl_xor(ns, 1); ns += __shfl_xor(ns, 2);
        ns += __shfl_xor(ns, 4); ns += __shfl_xor(ns, 8);
        ns += __shfl_xor(ns, 16);
        if (ln == 0) {
            int r = blk * 64 + i * 8 + sub;
            pos[r] = ps;                    // == scores[b][b], exact fp32
            loss1 += softplus_f(ns - ps);
        }
    }
    // wave-level sum then one atomic per wave
    loss1 += __shfl_xor(loss1, 1);  loss1 += __shfl_xor(loss1, 2);
    loss1 += __shfl_xor(loss1, 4);  loss1 += __shfl_xor(loss1, 8);
    loss1 += __shfl_xor(loss1, 16); loss1 += __shfl_xor(loss1, 32);
    if ((t & 63) == 0) atomicAdd(acc, loss1);
}

// ---------------------------------------------------------------------------
// Async stage of a 16-col x 128-k bf16 chunk into LDS with XOR-swizzled
// 16B k-segments (swizzle via the GLOBAL address; LDS dest of global_load_lds
// is fixed lane-linear). LDS: col c at c*256B; LDS slot s holds global seg s^c.
// ---------------------------------------------------------------------------
__device__ __forceinline__ void stage16(const ushort* __restrict__ db,
                                        ushort* lbuf, int colBase, int l)
{
#pragma unroll
    for (int i = 0; i < 4; ++i) {
        int c_local = i * 4 + (l >> 4);                 // 0..15
        int kseg    = (l & 15) ^ c_local;               // global 16B segment
        const ushort* g = db + (size_t)(colBase + c_local) * DDIM + kseg * 8;
        __builtin_amdgcn_global_load_lds(
            (const __attribute__((address_space(1))) void*)g,
            (__attribute__((address_space(3))) void*)(lbuf + i * 512),
            16, 0, 0);
    }
}

// ---------------------------------------------------------------------------
// Kernel B: fused GEMM + row-max. 256 blocks x 512 threads (8 waves, 1 blk/CU,
// 2 waves/SIMD). Block owns 64 rows (A-frags resident in registers). Waves
// split columns 8-way; each wave double-buffers its own private 16-col LDS
// chunks with explicit vmcnt waits -- no __syncthreads in the main loop.
// ---------------------------------------------------------------------------
__global__ __launch_bounds__(512, 2) void inbatch_kernel(
    const ushort* __restrict__ qb, const ushort* __restrict__ db,
    const float* __restrict__ pos, float* __restrict__ acc)
{
    __shared__ ushort stg[NWAVES][2][CHUNK_COLS * DDIM];   // 8 x 2 x 4KB = 64KB

    const int t      = threadIdx.x;
    const int w      = t >> 6;
    const int l      = t & 63;
    const int lane16 = l & 15;
    const int quad   = l >> 4;
    const int row0   = blockIdx.x * ROWS_PER_BLOCK;

    // A fragments: lane l holds Q[row0 + rs*16 + (l&15)][ks*32 + quad*8 + j]
    bf16x8 afrag[4][4];
#pragma unroll
    for (int rs = 0; rs < 4; ++rs)
#pragma unroll
        for (int ks = 0; ks < 4; ++ks)
            afrag[rs][ks] = *(const bf16x8*)(
                qb + (size_t)(row0 + rs * 16 + lane16) * DDIM + ks * 32 + quad * 8);

    float runmax[4][4];
#pragma unroll
    for (int rs = 0; rs < 4; ++rs)
#pragma unroll
        for (int r = 0; r < 4; ++r) runmax[rs][r] = -3.0e38f;

    const int colW = w * COLS_PER_WAVE;
    ushort* buf0 = &stg[w][0][0];
    ushort* buf1 = &stg[w][1][0];

    stage16(db, buf0, colW, l);   // prologue: chunk 0

    for (int ch = 0; ch < NCHUNKS; ++ch) {
        ushort* cur = (ch & 1) ? buf1 : buf0;
        ushort* nxt = (ch & 1) ? buf0 : buf1;
        if (ch + 1 < NCHUNKS) {
            stage16(db, nxt, colW + (ch + 1) * CHUNK_COLS, l);
            // 8 outstanding global_load_lds; wait until only the 4 newest
            // remain => current buffer complete. vmcnt(4); lgkm/exp untouched.
            __builtin_amdgcn_s_waitcnt(4 | (7 << 4) | (15 << 8));
        } else {
            __builtin_amdgcn_s_waitcnt(0 | (7 << 4) | (15 << 8));  // vmcnt(0)
        }
        asm volatile("" ::: "memory");   // don't hoist ds_reads above the wait

        // B fragments: lane l holds D[colBase + (l&15)][ks*32 + quad*8 + j]
        bf16x8 bfrag[4];
#pragma unroll
        for (int ks = 0; ks < 4; ++ks) {
            int kseg = ks * 4 + quad;
            bfrag[ks] = *(const bf16x8*)(
                cur + lane16 * DDIM + ((kseg ^ lane16) * 8));
        }

        const int cg0 = colW + ch * CHUNK_COLS;
#pragma unroll
        for (int rs = 0; rs < 4; ++rs) {
            f32x4 s = {0.0f, 0.0f, 0.0f, 0.0f};
#pragma unroll
            for (int ks = 0; ks < 4; ++ks)
                s = __builtin_amdgcn_mfma_f32_16x16x32_bf16(
                    afrag[rs][ks], bfrag[ks], s, 0, 0, 0);
            if (cg0 == row0 + rs * 16) {   // diagonal tile: scores - 1e6
#pragma unroll
                for (int r = 0; r < 4; ++r)
                    if (quad * 4 + r == lane16) s[r] -= 1.0e6f;
            }
#pragma unroll
            for (int r = 0; r < 4; ++r)
                runmax[rs][r] = fmaxf(runmax[rs][r], s[r]);
        }
    }

    // reduce max across the 16 lanes of each quad-group (same row, cols mod 16)
#pragma unroll
    for (int rs = 0; rs < 4; ++rs)
#pragma unroll
        for (int r = 0; r < 4; ++r) {
            float m = runmax[rs][r];
            m = fmaxf(m, __shfl_xor(m, 1));
            m = fmaxf(m, __shfl_xor(m, 2));
            m = fmaxf(m, __shfl_xor(m, 4));
            m = fmaxf(m, __shfl_xor(m, 8));
            runmax[rs][r] = m;
        }

    __syncthreads();                       // staging buffers now reusable
    float* smax = (float*)&stg[0][0][0];   // [8 waves][64 rows]
    if (lane16 == 0) {
#pragma unroll
        for (int rs = 0; rs < 4; ++rs)
#pragma unroll
            for (int r = 0; r < 4; ++r)
                smax[w * 64 + rs * 16 + quad * 4 + r] = runmax[rs][r];
    }
    __syncthreads();

    if (t < 64) {   // wave 0: combine 8 col-ranges, softplus, block sum
        float fm = smax[t];
#pragma unroll
        for (int ww = 1; ww < NWAVES; ++ww)
            fm = fmaxf(fm, smax[ww * 64 + t]);
        float c = softplus_f(fm - pos[row0 + t]);
        c += __shfl_xor(c, 1);  c += __shfl_xor(c, 2);
        c += __shfl_xor(c, 4);  c += __shfl_xor(c, 8);
        c += __shfl_xor(c, 16); c += __shfl_xor(c, 32);
        if (t == 0) atomicAdd(acc + 1, c);
    }
}

__global__ void finalize_kernel(const float* __restrict__ acc,
                                float* __restrict__ out)
{
    out[0] = (acc[0] + acc[1]) * (1.0f / (2.0f * BATCH));
}

extern "C" void kernel_launch(void* const* d_in, const int* in_sizes, int n_in,
                              void* d_out, int out_size, void* d_ws, size_t ws_size,
                              hipStream_t stream)
{
    const float* q  = (const float*)d_in[0];
    const float* d  = (const float*)d_in[1];
    const float* nd = (const float*)d_in[2];
    float* out = (float*)d_out;

    char* ws   = (char*)d_ws;
    float*  acc = (float*)ws;                            // 2 floats
    float*  pos = (float*)(ws + 256);                    // 16384 floats = 64KB
    ushort* qb  = (ushort*)(ws + 256 + 65536);           // 4MB bf16
    ushort* db  = (ushort*)(ws + 256 + 65536 + 4194304); // 4MB bf16

    hipMemsetAsync(acc, 0, 8, stream);
    prep_kernel<<<BATCH / 64, 256, 0, stream>>>(q, d, nd, qb, db, pos, acc);
    inbatch_kernel<<<BATCH / ROWS_PER_BLOCK, 512, 0, stream>>>(qb, db, pos, acc);
    finalize_kernel<<<1, 1, 0, stream>>>(acc, out);
}

// Round 3
// 150.609 us; speedup vs baseline: 1.1339x; 1.1339x over previous
//
#include <hip/hip_runtime.h>
#include <hip/hip_bf16.h>

// BiPairwiseNegativeCELoss on MI355X.
// Inputs: q, d, nd : [16384, 128] fp32. Output: scalar fp32 loss.
// loss = 0.5 * ( mean(softplus(q.nd_row - q.d_row))
//              + mean(softplus(max_c(q_b . d_c, diag -1e6) - q_b.d_b)) )

#define BATCH 16384
#define DDIM  128
#define ROWS_PER_BLOCK 64
#define NWAVES 8                // 512 threads: 2 waves/SIMD
#define COLS_PER_WAVE  (BATCH / NWAVES)               // 2048
#define CHUNK_COLS     16       // 16 cols x 128 k x bf16 = 4 KB per buffer
#define NCHUNKS        (COLS_PER_WAVE / CHUNK_COLS)   // 128
#define NBUF 4                  // quad buffer: prefetch distance 3
#define CHUNK_USHORTS  (CHUNK_COLS * DDIM)            // 2048

typedef __attribute__((ext_vector_type(8))) short bf16x8;   // 8 bf16 = 4 VGPRs
typedef __attribute__((ext_vector_type(4))) float f32x4;

__device__ __forceinline__ float softplus_f(float x) {
    return (x > 0.0f) ? x + log1pf(expf(-x)) : log1pf(expf(x));
}

__device__ __forceinline__ ushort f2bf_rne(float x) {
    unsigned u = __float_as_uint(x);
    unsigned r = (u + 0x7FFFu + ((u >> 16) & 1u)) >> 16;
    return (ushort)r;
}

// ---------------------------------------------------------------------------
// Kernel A: single pass over q/d/nd -- pairwise dots (fp32 exact), loss1
// partial sums, bf16 casts. 256 blocks x 256 threads; block owns 64 rows.
// ---------------------------------------------------------------------------
__global__ __launch_bounds__(256) void prep_kernel(
    const float* __restrict__ q, const float* __restrict__ d,
    const float* __restrict__ nd,
    ushort* __restrict__ qb, ushort* __restrict__ db,
    float* __restrict__ pos, float* __restrict__ acc)
{
    const int t   = threadIdx.x;
    const int blk = blockIdx.x;
    const int sub = t >> 5;
    const int ln  = t & 31;
    const size_t base = (size_t)blk * (ROWS_PER_BLOCK * DDIM);

    float loss1 = 0.0f;
#pragma unroll
    for (int i = 0; i < 8; ++i) {
        size_t idx = base + (size_t)i * 1024 + (size_t)t * 4;
        float4 a = *(const float4*)(q  + idx);
        float4 b = *(const float4*)(d  + idx);
        float4 c = *(const float4*)(nd + idx);

        ushort4 o;
        o.x = f2bf_rne(a.x); o.y = f2bf_rne(a.y);
        o.z = f2bf_rne(a.z); o.w = f2bf_rne(a.w);
        *(ushort4*)(qb + idx) = o;
        ushort4 p;
        p.x = f2bf_rne(b.x); p.y = f2bf_rne(b.y);
        p.z = f2bf_rne(b.z); p.w = f2bf_rne(b.w);
        *(ushort4*)(db + idx) = p;

        float ps = a.x * b.x + a.y * b.y + a.z * b.z + a.w * b.w;
        float ns = a.x * c.x + a.y * c.y + a.z * c.z + a.w * c.w;
        ps += __shfl_xor(ps, 1); ps += __shfl_xor(ps, 2);
        ps += __shfl_xor(ps, 4); ps += __shfl_xor(ps, 8);
        ps += __shfl_xor(ps, 16);
        ns += __shfl_xor(ns, 1); ns += __shfl_xor(ns, 2);
        ns += __shfl_xor(ns, 4); ns += __shfl_xor(ns, 8);
        ns += __shfl_xor(ns, 16);
        if (ln == 0) {
            int r = blk * 64 + i * 8 + sub;
            pos[r] = ps;
            loss1 += softplus_f(ns - ps);
        }
    }
    loss1 += __shfl_xor(loss1, 1);  loss1 += __shfl_xor(loss1, 2);
    loss1 += __shfl_xor(loss1, 4);  loss1 += __shfl_xor(loss1, 8);
    loss1 += __shfl_xor(loss1, 16); loss1 += __shfl_xor(loss1, 32);
    if ((t & 63) == 0) atomicAdd(acc, loss1);
}

// ---------------------------------------------------------------------------
// Async stage of a 16-col x 128-k bf16 chunk into LDS. XOR swizzle applied on
// the GLOBAL source address (LDS dest of global_load_lds is lane-linear):
// LDS slot s of col c holds global 16B-segment s^c.
// ---------------------------------------------------------------------------
__device__ __forceinline__ void stage16(const ushort* __restrict__ db,
                                        ushort* lbuf, int colBase, int l)
{
#pragma unroll
    for (int i = 0; i < 4; ++i) {
        int c_local = i * 4 + (l >> 4);                 // 0..15
        int kseg    = (l & 15) ^ c_local;               // global 16B segment
        const ushort* g = db + (size_t)(colBase + c_local) * DDIM + kseg * 8;
        __builtin_amdgcn_global_load_lds(
            (const __attribute__((address_space(1))) void*)g,
            (__attribute__((address_space(3))) void*)(lbuf + i * 512),
            16, 0, 0);
    }
}

// ---------------------------------------------------------------------------
// Kernel B: fused GEMM + row-max. 256 blocks x 512 threads, 1 block/CU,
// 2 waves/SIMD. 128 KB dynamic LDS: 8 waves x QUAD-buffered private 16-col
// chunks, prefetch distance 3, explicit vmcnt(12) -- no __syncthreads in the
// main loop. ds_read addresses precomputed once (buffer select by immediate).
// ---------------------------------------------------------------------------
__global__ __launch_bounds__(512, 2) void inbatch_kernel(
    const ushort* __restrict__ qb, const ushort* __restrict__ db,
    const float* __restrict__ pos, float* __restrict__ acc)
{
    extern __shared__ ushort stg[];   // [NWAVES][NBUF][CHUNK_USHORTS] = 128 KB

    const int t      = threadIdx.x;
    const int w      = t >> 6;
    const int l      = t & 63;
    const int lane16 = l & 15;
    const int quad   = l >> 4;
    const int row0   = blockIdx.x * ROWS_PER_BLOCK;

    ushort* wbase = stg + (size_t)w * (NBUF * CHUNK_USHORTS);

    // A fragments: lane l holds Q[row0 + rs*16 + (l&15)][ks*32 + quad*8 + j]
    bf16x8 afrag[4][4];
#pragma unroll
    for (int rs = 0; rs < 4; ++rs)
#pragma unroll
        for (int ks = 0; ks < 4; ++ks)
            afrag[rs][ks] = *(const bf16x8*)(
                qb + (size_t)(row0 + rs * 16 + lane16) * DDIM + ks * 32 + quad * 8);

    // ds_read base addresses for buffer 0, one per ks (buffer b = +4096*b imm)
    const ushort* dsaddr[4];
#pragma unroll
    for (int ks = 0; ks < 4; ++ks)
        dsaddr[ks] = wbase + lane16 * DDIM + (((ks * 4 + quad) ^ lane16) * 8);

    float runmax[4][4];
#pragma unroll
    for (int rs = 0; rs < 4; ++rs)
#pragma unroll
        for (int r = 0; r < 4; ++r) runmax[rs][r] = -3.0e38f;

    const int colW = w * COLS_PER_WAVE;

    // compute on buffer `b` (compile-time), columns [cg0, cg0+16)
#define COMPUTE_CHUNK(b, cg0)                                                  \
    do {                                                                       \
        bf16x8 bfrag[4];                                                       \
        _Pragma("unroll")                                                      \
        for (int ks = 0; ks < 4; ++ks)                                         \
            bfrag[ks] = *(const bf16x8*)(dsaddr[ks] + (b) * CHUNK_USHORTS);    \
        _Pragma("unroll")                                                      \
        for (int rs = 0; rs < 4; ++rs) {                                       \
            f32x4 s = {0.0f, 0.0f, 0.0f, 0.0f};                                \
            _Pragma("unroll")                                                  \
            for (int ks = 0; ks < 4; ++ks)                                     \
                s = __builtin_amdgcn_mfma_f32_16x16x32_bf16(                   \
                    afrag[rs][ks], bfrag[ks], s, 0, 0, 0);                     \
            if ((cg0) == row0 + rs * 16) {                                     \
                _Pragma("unroll")                                              \
                for (int r = 0; r < 4; ++r)                                    \
                    if (quad * 4 + r == lane16) s[r] -= 1.0e6f;                \
            }                                                                  \
            _Pragma("unroll")                                                  \
            for (int r = 0; r < 4; ++r)                                        \
                runmax[rs][r] = fmaxf(runmax[rs][r], s[r]);                    \
        }                                                                      \
    } while (0)

#define WAITVM(n) do { \
        __builtin_amdgcn_s_waitcnt((n) | (7 << 4) | (15 << 8)); \
        asm volatile("" ::: "memory"); \
    } while (0)

    // prologue: stage chunks 0,1,2
    stage16(db, wbase + 0 * CHUNK_USHORTS, colW + 0 * CHUNK_COLS, l);
    stage16(db, wbase + 1 * CHUNK_USHORTS, colW + 1 * CHUNK_COLS, l);
    stage16(db, wbase + 2 * CHUNK_USHORTS, colW + 2 * CHUNK_COLS, l);

    // main loop: ch = 0 .. NCHUNKS-5, unrolled x4 for static buffer indices
    for (int u = 0; u < NCHUNKS / 4 - 1; ++u) {
        const int ch0 = u * 4;
#pragma unroll
        for (int j = 0; j < 4; ++j) {
            const int ch = ch0 + j;
            stage16(db, wbase + ((j + 3) & 3) * CHUNK_USHORTS,
                    colW + (ch + 3) * CHUNK_COLS, l);
            WAITVM(12);
            COMPUTE_CHUNK(j, colW + ch * CHUNK_COLS);
        }
    }
    // peeled tail: ch = NCHUNKS-4 .. NCHUNKS-1
    {
        const int ch = NCHUNKS - 4;
        stage16(db, wbase + 3 * CHUNK_USHORTS,
                colW + (NCHUNKS - 1) * CHUNK_COLS, l);
        WAITVM(12);
        COMPUTE_CHUNK(0, colW + ch * CHUNK_COLS);
        WAITVM(8);
        COMPUTE_CHUNK(1, colW + (ch + 1) * CHUNK_COLS);
        WAITVM(4);
        COMPUTE_CHUNK(2, colW + (ch + 2) * CHUNK_COLS);
        WAITVM(0);
        COMPUTE_CHUNK(3, colW + (ch + 3) * CHUNK_COLS);
    }

    // reduce max across the 16 lanes of each quad-group
#pragma unroll
    for (int rs = 0; rs < 4; ++rs)
#pragma unroll
        for (int r = 0; r < 4; ++r) {
            float m = runmax[rs][r];
            m = fmaxf(m, __shfl_xor(m, 1));
            m = fmaxf(m, __shfl_xor(m, 2));
            m = fmaxf(m, __shfl_xor(m, 4));
            m = fmaxf(m, __shfl_xor(m, 8));
            runmax[rs][r] = m;
        }

    __syncthreads();                 // staging buffers now reusable
    float* smax = (float*)stg;       // [8 waves][64 rows]
    if (lane16 == 0) {
#pragma unroll
        for (int rs = 0; rs < 4; ++rs)
#pragma unroll
            for (int r = 0; r < 4; ++r)
                smax[w * 64 + rs * 16 + quad * 4 + r] = runmax[rs][r];
    }
    __syncthreads();

    if (t < 64) {   // wave 0: combine 8 col-ranges, softplus, block sum
        float fm = smax[t];
#pragma unroll
        for (int ww = 1; ww < NWAVES; ++ww)
            fm = fmaxf(fm, smax[ww * 64 + t]);
        float c = softplus_f(fm - pos[row0 + t]);
        c += __shfl_xor(c, 1);  c += __shfl_xor(c, 2);
        c += __shfl_xor(c, 4);  c += __shfl_xor(c, 8);
        c += __shfl_xor(c, 16); c += __shfl_xor(c, 32);
        if (t == 0) atomicAdd(acc + 1, c);
    }
#undef COMPUTE_CHUNK
#undef WAITVM
}

__global__ void finalize_kernel(const float* __restrict__ acc,
                                float* __restrict__ out)
{
    out[0] = (acc[0] + acc[1]) * (1.0f / (2.0f * BATCH));
}

extern "C" void kernel_launch(void* const* d_in, const int* in_sizes, int n_in,
                              void* d_out, int out_size, void* d_ws, size_t ws_size,
                              hipStream_t stream)
{
    const float* q  = (const float*)d_in[0];
    const float* d  = (const float*)d_in[1];
    const float* nd = (const float*)d_in[2];
    float* out = (float*)d_out;

    char* ws   = (char*)d_ws;
    float*  acc = (float*)ws;                            // 2 floats
    float*  pos = (float*)(ws + 256);                    // 16384 floats = 64KB
    ushort* qb  = (ushort*)(ws + 256 + 65536);           // 4MB bf16
    ushort* db  = (ushort*)(ws + 256 + 65536 + 4194304); // 4MB bf16

    const int lds_bytes = NWAVES * NBUF * CHUNK_USHORTS * (int)sizeof(ushort); // 128KB
    static bool attr_set = false;    // host-side only; same work every call
    if (!attr_set) {
        hipFuncSetAttribute((const void*)inbatch_kernel,
                            hipFuncAttributeMaxDynamicSharedMemorySize, lds_bytes);
        attr_set = true;
    }

    hipMemsetAsync(acc, 0, 8, stream);
    prep_kernel<<<BATCH / 64, 256, 0, stream>>>(q, d, nd, qb, db, pos, acc);
    inbatch_kernel<<<BATCH / ROWS_PER_BLOCK, 512, lds_bytes, stream>>>(qb, db, pos, acc);
    finalize_kernel<<<1, 1, 0, stream>>>(acc, out);
}

// Round 4
// 141.612 us; speedup vs baseline: 1.2060x; 1.0635x over previous
//
#include <hip/hip_runtime.h>
#include <hip/hip_bf16.h>

// BiPairwiseNegativeCELoss on MI355X.
// Inputs: q, d, nd : [16384, 128] fp32. Output: scalar fp32 loss.
// loss = 0.5 * ( mean(softplus(q.nd_row - q.d_row))
//              + mean(softplus(max_c(q_b . d_c, diag -1e6) - q_b.d_b)) )
//
// R4: 2D score-matrix tiling. 256 blocks = 32 row-groups x 8 col-groups;
// block = 512 rows x 2048 cols. L2 traffic 1 GB -> 160 MB (r3's L2 floor
// removed). B chunks (128 cols) cooperatively staged, double-buffered,
// ~4100 cyc MFMA per barrier. Row-max partials -> global, reduce kernel.

#define BATCH 16384
#define DDIM  128
#define NWAVES 8                 // 512 threads, 2 waves/SIMD
#define ROWS_PER_BLOCK 512       // 8 waves x 64 rows
#define COLS_PER_BLOCK 2048      // 8 col-groups
#define CHUNK_COLS 128           // 32 KB bf16 per chunk
#define NCHUNKS (COLS_PER_BLOCK / CHUNK_COLS)   // 16
#define CHUNK_USHORTS (CHUNK_COLS * DDIM)       // 16384
#define NCG (BATCH / COLS_PER_BLOCK)            // 8

typedef __attribute__((ext_vector_type(8))) short bf16x8;   // 8 bf16 = 4 VGPRs
typedef __attribute__((ext_vector_type(4))) float f32x4;

__device__ __forceinline__ float softplus_f(float x) {
    return (x > 0.0f) ? x + log1pf(expf(-x)) : log1pf(expf(x));
}

__device__ __forceinline__ ushort f2bf_rne(float x) {
    unsigned u = __float_as_uint(x);
    unsigned r = (u + 0x7FFFu + ((u >> 16) & 1u)) >> 16;
    return (ushort)r;
}

#define WAITVM(n) do { \
        __builtin_amdgcn_s_waitcnt((n) | (7 << 4) | (15 << 8)); \
        asm volatile("" ::: "memory"); \
    } while (0)

// ---------------------------------------------------------------------------
// Kernel A: single pass over q/d/nd -- pairwise dots (fp32 exact), loss1
// partial sums, bf16 casts. 256 blocks x 256 threads; block owns 64 rows.
// ---------------------------------------------------------------------------
__global__ __launch_bounds__(256) void prep_kernel(
    const float* __restrict__ q, const float* __restrict__ d,
    const float* __restrict__ nd,
    ushort* __restrict__ qb, ushort* __restrict__ db,
    float* __restrict__ pos, float* __restrict__ acc)
{
    const int t   = threadIdx.x;
    const int blk = blockIdx.x;
    const int sub = t >> 5;
    const int ln  = t & 31;
    const size_t base = (size_t)blk * (64 * DDIM);

    float loss1 = 0.0f;
#pragma unroll
    for (int i = 0; i < 8; ++i) {
        size_t idx = base + (size_t)i * 1024 + (size_t)t * 4;
        float4 a = *(const float4*)(q  + idx);
        float4 b = *(const float4*)(d  + idx);
        float4 c = *(const float4*)(nd + idx);

        ushort4 o;
        o.x = f2bf_rne(a.x); o.y = f2bf_rne(a.y);
        o.z = f2bf_rne(a.z); o.w = f2bf_rne(a.w);
        *(ushort4*)(qb + idx) = o;
        ushort4 p;
        p.x = f2bf_rne(b.x); p.y = f2bf_rne(b.y);
        p.z = f2bf_rne(b.z); p.w = f2bf_rne(b.w);
        *(ushort4*)(db + idx) = p;

        float ps = a.x * b.x + a.y * b.y + a.z * b.z + a.w * b.w;
        float ns = a.x * c.x + a.y * c.y + a.z * c.z + a.w * c.w;
        ps += __shfl_xor(ps, 1); ps += __shfl_xor(ps, 2);
        ps += __shfl_xor(ps, 4); ps += __shfl_xor(ps, 8);
        ps += __shfl_xor(ps, 16);
        ns += __shfl_xor(ns, 1); ns += __shfl_xor(ns, 2);
        ns += __shfl_xor(ns, 4); ns += __shfl_xor(ns, 8);
        ns += __shfl_xor(ns, 16);
        if (ln == 0) {
            int r = blk * 64 + i * 8 + sub;
            pos[r] = ps;
            loss1 += softplus_f(ns - ps);
        }
    }
    loss1 += __shfl_xor(loss1, 1);  loss1 += __shfl_xor(loss1, 2);
    loss1 += __shfl_xor(loss1, 4);  loss1 += __shfl_xor(loss1, 8);
    loss1 += __shfl_xor(loss1, 16); loss1 += __shfl_xor(loss1, 32);
    if ((t & 63) == 0) atomicAdd(acc, loss1);
}

// ---------------------------------------------------------------------------
// Kernel B: fused GEMM + row-max. 256 blocks x 512 threads, 1 block/CU.
// Block (rg = bx&31, cg = bx>>5): rows [rg*512, +512), cols [cg*2048, +2048).
// Wave w owns 64 rows (A in registers, whole K). B staged cooperatively:
// 128-col chunks, 2x32KB LDS double buffer, XOR-swizzled 16B k-segments
// (swizzle on the GLOBAL address; LDS dest of global_load_lds is lane-linear:
// LDS slot s of col c holds global segment s ^ (c&15)).
// ---------------------------------------------------------------------------
__global__ __launch_bounds__(512, 2) void inbatch_kernel(
    const ushort* __restrict__ qb, const ushort* __restrict__ db,
    float* __restrict__ partials)
{
    __shared__ ushort stg[2][CHUNK_USHORTS];   // 2 x 32 KB

    const int t      = threadIdx.x;
    const int w      = t >> 6;
    const int l      = t & 63;
    const int lane16 = l & 15;
    const int quad   = l >> 4;
    const int rg     = blockIdx.x & 31;
    const int cg     = blockIdx.x >> 5;
    const int rows0  = rg * ROWS_PER_BLOCK + w * 64;   // this wave's 64 rows
    const int col0   = cg * COLS_PER_BLOCK;

    // A fragments: lane l holds Q[rows0 + rs*16 + (l&15)][ks*32 + quad*8 + j]
    bf16x8 afrag[4][4];
#pragma unroll
    for (int rs = 0; rs < 4; ++rs)
#pragma unroll
        for (int ks = 0; ks < 4; ++ks)
            afrag[rs][ks] = *(const bf16x8*)(
                qb + (size_t)(rows0 + rs * 16 + lane16) * DDIM + ks * 32 + quad * 8);

    // staging: thread t handles 16B segments i*512 + t (i = 0..3) of each
    // chunk; seg -> col = seg>>4, LDS slot = seg&15, global kseg = slot^(col&15)
    const ushort* gsrc[4];
#pragma unroll
    for (int i = 0; i < 4; ++i) {
        int seg = i * 512 + t;
        int c   = seg >> 4;
        int s   = seg & 15;
        gsrc[i] = db + (size_t)(col0 + c) * DDIM + ((s ^ (c & 15)) * 8);
    }

    // ds_read base (ushort offsets); per-(ct,buf) selected by immediate offset
    int dsbase[4];
#pragma unroll
    for (int ks = 0; ks < 4; ++ks)
        dsbase[ks] = lane16 * DDIM + (((ks * 4 + quad) ^ lane16) * 8);

    float runmax[4][4];
#pragma unroll
    for (int rs = 0; rs < 4; ++rs)
#pragma unroll
        for (int r = 0; r < 4; ++r) runmax[rs][r] = -3.0e38f;

    // prologue: stage chunk 0 into buf 0 (LDS dest wave-uniform + lane*16B)
#pragma unroll
    for (int i = 0; i < 4; ++i)
        __builtin_amdgcn_global_load_lds(
            (const __attribute__((address_space(1))) void*)gsrc[i],
            (__attribute__((address_space(3))) void*)(&stg[0][0] + (i * 512 + w * 64) * 8),
            16, 0, 0);

    for (int ch = 0; ch < NCHUNKS; ++ch) {
        WAITVM(0);
        __syncthreads();                     // chunk ch visible; buf ch^1 free
        if (ch + 1 < NCHUNKS) {              // prefetch next chunk now; it has
#pragma unroll                               // the whole compute phase to land
            for (int i = 0; i < 4; ++i)
                __builtin_amdgcn_global_load_lds(
                    (const __attribute__((address_space(1))) void*)(gsrc[i] + (size_t)(ch + 1) * CHUNK_USHORTS),
                    (__attribute__((address_space(3))) void*)(&stg[(ch + 1) & 1][0] + (i * 512 + w * 64) * 8),
                    16, 0, 0);
        }

        const ushort* buf = &stg[ch & 1][0];
#pragma unroll
        for (int ct = 0; ct < 8; ++ct) {
            bf16x8 bfrag[4];
#pragma unroll
            for (int ks = 0; ks < 4; ++ks)
                bfrag[ks] = *(const bf16x8*)(buf + dsbase[ks] + ct * 2048);

            const int ctile = col0 + ch * CHUNK_COLS + ct * 16;
#pragma unroll
            for (int rs = 0; rs < 4; ++rs) {
                f32x4 s = {0.0f, 0.0f, 0.0f, 0.0f};
#pragma unroll
                for (int ks = 0; ks < 4; ++ks)
                    s = __builtin_amdgcn_mfma_f32_16x16x32_bf16(
                        afrag[rs][ks], bfrag[ks], s, 0, 0, 0);
                if (ctile == rows0 + rs * 16) {    // diagonal tile: -1e6
#pragma unroll
                    for (int r = 0; r < 4; ++r)
                        if (quad * 4 + r == lane16) s[r] -= 1.0e6f;
                }
#pragma unroll
                for (int r = 0; r < 4; ++r)
                    runmax[rs][r] = fmaxf(runmax[rs][r], s[r]);
            }
        }
    }

    // reduce max across the 16 lanes (cols) of each quad-group
#pragma unroll
    for (int rs = 0; rs < 4; ++rs)
#pragma unroll
        for (int r = 0; r < 4; ++r) {
            float m = runmax[rs][r];
            m = fmaxf(m, __shfl_xor(m, 1));
            m = fmaxf(m, __shfl_xor(m, 2));
            m = fmaxf(m, __shfl_xor(m, 4));
            m = fmaxf(m, __shfl_xor(m, 8));
            runmax[rs][r] = m;
        }

    // partial row-max for this col-group -> global [NCG][BATCH]
    if (lane16 == 0) {
#pragma unroll
        for (int rs = 0; rs < 4; ++rs)
#pragma unroll
            for (int r = 0; r < 4; ++r)
                partials[(size_t)cg * BATCH + rows0 + rs * 16 + quad * 4 + r] =
                    runmax[rs][r];
    }
}

// ---------------------------------------------------------------------------
// Kernel C: combine col-group partials, softplus, sum into acc[1].
// ---------------------------------------------------------------------------
__global__ __launch_bounds__(256) void reduce_kernel(
    const float* __restrict__ partials, const float* __restrict__ pos,
    float* __restrict__ acc)
{
    const int r = blockIdx.x * 256 + threadIdx.x;
    float fm = partials[r];
#pragma unroll
    for (int cgi = 1; cgi < NCG; ++cgi)
        fm = fmaxf(fm, partials[(size_t)cgi * BATCH + r]);
    float c = softplus_f(fm - pos[r]);
    c += __shfl_xor(c, 1);  c += __shfl_xor(c, 2);
    c += __shfl_xor(c, 4);  c += __shfl_xor(c, 8);
    c += __shfl_xor(c, 16); c += __shfl_xor(c, 32);
    if ((threadIdx.x & 63) == 0) atomicAdd(acc + 1, c);
}

__global__ void finalize_kernel(const float* __restrict__ acc,
                                float* __restrict__ out)
{
    out[0] = (acc[0] + acc[1]) * (1.0f / (2.0f * BATCH));
}

extern "C" void kernel_launch(void* const* d_in, const int* in_sizes, int n_in,
                              void* d_out, int out_size, void* d_ws, size_t ws_size,
                              hipStream_t stream)
{
    const float* q  = (const float*)d_in[0];
    const float* d  = (const float*)d_in[1];
    const float* nd = (const float*)d_in[2];
    float* out = (float*)d_out;

    char* ws = (char*)d_ws;
    float*  acc      = (float*)ws;                              // 2 floats
    float*  pos      = (float*)(ws + 256);                      // 64 KB
    ushort* qb       = (ushort*)(ws + 256 + 65536);             // 4 MB
    ushort* db       = (ushort*)(ws + 256 + 65536 + 4194304);   // 4 MB
    float*  partials = (float*)(ws + 256 + 65536 + 2 * 4194304); // 512 KB

    hipMemsetAsync(acc, 0, 8, stream);
    prep_kernel<<<BATCH / 64, 256, 0, stream>>>(q, d, nd, qb, db, pos, acc);
    inbatch_kernel<<<(BATCH / ROWS_PER_BLOCK) * NCG, 512, 0, stream>>>(qb, db, partials);
    reduce_kernel<<<BATCH / 256, 256, 0, stream>>>(partials, pos, acc);
    finalize_kernel<<<1, 1, 0, stream>>>(acc, out);
}